// Round 13
// baseline (157.071 us; speedup 1.0000x reference)
//
#include <hip/hip_runtime.h>
#include <hip/hip_bf16.h>
#include <stdint.h>
#include <stddef.h>

// ---------- types ----------
typedef __attribute__((ext_vector_type(8))) short bf16x8;   // 8 bf16 (4 VGPR)
typedef __attribute__((ext_vector_type(4))) short bf16x4;   // 4 bf16 (2 VGPR)
typedef __attribute__((ext_vector_type(4))) float f32x4;
typedef __attribute__((ext_vector_type(4))) unsigned short u16x4;
typedef __attribute__((ext_vector_type(4))) unsigned int u32x4;

#define DEVI static __device__ __forceinline__

// problem constants
static constexpr int BATCH = 4;
static constexpr int SEQ   = 2048;
static constexpr int DMODEL = 1024;
static constexpr int MROWS = BATCH * SEQ;          // 8192

DEVI unsigned short f2bf(float f) {
  union { float f; unsigned int u; } c; c.f = f;
  unsigned int u = c.u;
  unsigned int r = u + 0x7fffu + ((u >> 16) & 1u);   // RNE
  return (unsigned short)(r >> 16);
}

DEVI unsigned int fbits(float f) {
  union { float f; unsigned int u; } c; c.f = f;
  return c.u;
}

DEVI void gload_lds16(const void* g, void* l) {
  __builtin_amdgcn_global_load_lds(
      (const __attribute__((address_space(1))) void*)g,
      (__attribute__((address_space(3))) void*)l, 16, 0, 0);
}

// ---------- fused fp32 -> bf16 converts (one launch replaces five) ----------
__global__ void cvt_fuse(const float* __restrict__ x,  const float* __restrict__ WQ,
                         const float* __restrict__ WK, const float* __restrict__ WV,
                         const float* __restrict__ WO,
                         unsigned short* __restrict__ xb,
                         unsigned short* __restrict__ Wqk,
                         unsigned short* __restrict__ WVb,
                         unsigned short* __restrict__ WOt) {
  const int bid = blockIdx.x, tid = threadIdx.x;
  if (bid < 11264) {
    const float* src;
    unsigned short* dst;
    int i;
    if (bid < 8192)       { src = x;  dst = xb;            i = bid * 256 + tid; }
    else if (bid < 9216)  { src = WQ; dst = Wqk;           i = (bid - 8192) * 256 + tid; }
    else if (bid < 10240) { src = WK; dst = Wqk + 1048576; i = (bid - 9216) * 256 + tid; }
    else                  { src = WV; dst = WVb;           i = (bid - 10240) * 256 + tid; }
    f32x4 v = *(const f32x4*)(src + (size_t)i * 4);
    u16x4 o;
    o[0] = f2bf(v[0]); o[1] = f2bf(v[1]); o[2] = f2bf(v[2]); o[3] = f2bf(v[3]);
    *(u16x4*)(dst + (size_t)i * 4) = o;
  } else {
    const int i = (bid - 11264) * 256 + tid;     // 1M threads
    const int d = i >> 10, k = i & 1023;
    const int h = k >> 6, v = k & 63;
    WOt[i] = f2bf(WO[(size_t)(h * 1024 + d) * 64 + v]);
  }
}

// ---------- bf16 GEMM (128x128 tile), single-barrier double-buffer [verified] ----------
template <bool OUTBF>
__global__ __launch_bounds__(256)
void gemm_bt(const unsigned short* __restrict__ A,
             const unsigned short* __restrict__ Bt,
             void* __restrict__ Cv, int M, int N, int K, int ldc,
             float cscale, int scale_cols) {
  __shared__ unsigned short As[2][128 * 64];
  __shared__ unsigned short Bs[2][128 * 64];
  const int tid = threadIdx.x;
  const int lane = tid & 63;
  const int w = tid >> 6;
  const int wr = w >> 1, wc = w & 1;
  const int l15 = lane & 15, l4 = lane >> 4;
  const int nbn = N >> 7;
  const int nwg = gridDim.x;
  const int bid = (blockIdx.x & 7) * (nwg >> 3) + (blockIdx.x >> 3);
  const int mblk = bid / nbn, nblk = bid % nbn;
  const unsigned short* Ab = A + (size_t)mblk * 128 * K;
  const unsigned short* Bb = Bt + (size_t)nblk * 128 * K;
  f32x4 acc[4][4] = {};

  const int srow = tid >> 3;
  const int spos = tid & 7;
  const int nk = K >> 6;

  auto STAGE = [&](int buf, int t) {
    const int k0 = t * 64;
#pragma unroll
    for (int i = 0; i < 4; ++i) {
      const int row = srow + i * 32;
      const int sc = spos ^ (row & 7);
      gload_lds16(Ab + (size_t)row * K + k0 + sc * 8, (void*)(As[buf] + (tid + i * 256) * 8));
      gload_lds16(Bb + (size_t)row * K + k0 + sc * 8, (void*)(Bs[buf] + (tid + i * 256) * 8));
    }
  };

  auto COMPUTE = [&](const unsigned short* Asb, const unsigned short* Bsb) {
    bf16x8 af[2][4], bq[2][4];
#pragma unroll
    for (int cc = 0; cc < 2; ++cc) {
#pragma unroll
      for (int m = 0; m < 4; ++m) {
        const int ra = wr * 64 + m * 16 + l15;
        af[cc][m] = *(const bf16x8*)(Asb + ra * 64 + (((cc * 4 + l4) ^ (ra & 7)) * 8));
        const int rb = wc * 64 + m * 16 + l15;
        bq[cc][m] = *(const bf16x8*)(Bsb + rb * 64 + (((cc * 4 + l4) ^ (rb & 7)) * 8));
      }
    }
#pragma unroll
    for (int cc = 0; cc < 2; ++cc)
#pragma unroll
      for (int m = 0; m < 4; ++m)
#pragma unroll
        for (int n = 0; n < 4; ++n)
          acc[m][n] = __builtin_amdgcn_mfma_f32_16x16x32_bf16(af[cc][m], bq[cc][n], acc[m][n], 0, 0, 0);
  };

  STAGE(0, 0);
  __syncthreads();

  int t = 0;
  while (t + 1 < nk) {
    STAGE(1, t + 1);
    COMPUTE(As[0], Bs[0]);
    __syncthreads();
    if (t + 2 < nk) STAGE(0, t + 2);
    COMPUTE(As[1], Bs[1]);
    __syncthreads();
    t += 2;
  }
  if (t < nk) COMPUTE(As[0], Bs[0]);

#pragma unroll
  for (int m = 0; m < 4; ++m)
#pragma unroll
    for (int n = 0; n < 4; ++n) {
      int col = nblk * 128 + wc * 64 + n * 16 + l15;
      const float s = (col < scale_cols) ? cscale : 1.f;
#pragma unroll
      for (int j = 0; j < 4; ++j) {
        int row = mblk * 128 + wr * 64 + m * 16 + l4 * 4 + j;
        if (OUTBF)
          ((unsigned short*)Cv)[(size_t)row * ldc + col] = f2bf(acc[m][n][j] * s);
        else
          ((float*)Cv)[(size_t)row * ldc + col] = acc[m][n][j] * s;
      }
    }
}

// ---------- flash attention (causal), v11 ----------
// v10 (verified) reshaped to 32 q/wave (BQ=128/block): the SAME 16 b128
// K/V-frag reads per tile now feed 36 MFMAs (two 16-q halves) instead of 18
// -> LDS read traffic per q halves. attn was measured AT the b128 LDS-BW
// ceiling (~43 TB/s), so traffic, not MFMA, sets the wall.
// Per-wave tile count myNt = 2qi+1+(w>>1) skips each wave's fully-masked
// final tile (wave-uniform; barriers stay uniform over nt staged tiles).
// All index math (koff/voff swizzles, trunc-pack, ones-MFMA) v10-verified.
__global__ __launch_bounds__(256, 4)
void attn_fwd(const unsigned short* __restrict__ QKb,
              const unsigned short* __restrict__ Vt,
              unsigned short* __restrict__ Oout) {
  __shared__ unsigned short Ks[2][64 * 64];
  __shared__ unsigned short Vs[2][64 * 64];
  const int bid = blockIdx.x;
  const int qi = 15 - (bid >> 6);          // reversed: heavy blocks dispatch first
  const int bh = bid & 63;
  const int b = bh >> 4, h = bh & 15;
  const int tid = threadIdx.x, lane = tid & 63, w = tid >> 6;
  const int l15 = lane & 15, l4 = lane >> 4;
  const int qbase = qi * 128 + w * 32;     // wave's 32 q rows (two 16-row halves)
  const int LDQ = 2048;

  // Q fragments for both halves (Q pre-scaled by (1/sqrt(64))*log2(e))
  bf16x8 Qf[2][2];
#pragma unroll
  for (int hh = 0; hh < 2; ++hh) {
    const size_t qrow = (size_t)(b * SEQ + qbase + hh * 16 + l15) * LDQ + h * 64;
    Qf[hh][0] = *(const bf16x8*)(QKb + qrow + l4 * 8);
    Qf[hh][1] = *(const bf16x8*)(QKb + qrow + 32 + l4 * 8);
  }

  const unsigned short* Kbase = QKb + (size_t)b * SEQ * LDQ + 1024 + h * 64;
  const unsigned short* Vbase = Vt + (size_t)(h * 64) * MROWS + (size_t)b * SEQ;

  f32x4 O[2][4] = {};
  f32x4 Ol2[2] = {};                           // per-half P row-sums
  const int nt = 2 * qi + 2;                   // staged tiles (block-uniform, even)
  const int myNt = 2 * qi + 1 + (w >> 1);      // tiles this wave computes

  // ---- hoisted LDS offsets (v10-verified formulas) ----
  int koff[2][2][2];   // [jb][kg][cc]; K rows r = jb*32 + (l15>>2)*8 + kg*4 + (l15&3)
#pragma unroll
  for (int jb = 0; jb < 2; ++jb)
#pragma unroll
    for (int kg = 0; kg < 2; ++kg) {
      const int r = jb * 32 + (l15 >> 2) * 8 + kg * 4 + (l15 & 3);
      const int fk = ((r & 7) + ((r >> 3) & 1) * 4) & 7;
#pragma unroll
      for (int cc = 0; cc < 2; ++cc)
        koff[jb][kg][cc] = r * 64 + (((cc * 4 + l4) ^ fk) * 8);
    }
  int voff[2][4];      // [jb][vb] (b128 V reads)
#pragma unroll
  for (int jb = 0; jb < 2; ++jb)
#pragma unroll
    for (int vb = 0; vb < 4; ++vb) {
      const int vr = vb * 16 + l15;
      voff[jb][vb] = vr * 64 + (((4 * jb + l4) ^ (vr & 7)) * 8);
    }

  const int srow = tid >> 3, spos = tid & 7;
  const int fkS = (((srow & 7) + ((srow >> 3) & 1) * 4) & 7);
  const int scK = (spos ^ fkS) * 8;
  const int scV = (spos ^ (srow & 7)) * 8;
  const unsigned short* KsrcA = Kbase + (size_t)srow * LDQ + scK;
  const unsigned short* KsrcB = Kbase + (size_t)(srow + 32) * LDQ + scK;
  const unsigned short* VsrcA = Vbase + (size_t)srow * MROWS + scV;
  const unsigned short* VsrcB = Vbase + (size_t)(srow + 32) * MROWS + scV;

  auto STAGE = [&](int buf, int t) {
    const int kv0 = t * 64;
    gload_lds16(KsrcA + (size_t)kv0 * LDQ, (void*)(Ks[buf] + tid * 8));
    gload_lds16(KsrcB + (size_t)kv0 * LDQ, (void*)(Ks[buf] + (tid + 256) * 8));
    gload_lds16(VsrcA + kv0, (void*)(Vs[buf] + tid * 8));
    gload_lds16(VsrcB + kv0, (void*)(Vs[buf] + (tid + 256) * 8));
  };

  const bf16x8 ones8 = { (short)0x3F80, (short)0x3F80, (short)0x3F80, (short)0x3F80,
                         (short)0x3F80, (short)0x3F80, (short)0x3F80, (short)0x3F80 };

  auto COMPUTE = [&](const unsigned short* Kt, const unsigned short* Vv, int t) {
    const bool diag = (t == myNt - 1);
    // ---- QK^T: each K-frag pair read ONCE, used by both q-halves ----
    f32x4 Tm[2][2][2];   // [hh][jb][kg]; score at kv_loc = jb*32+l4*8+kg*4+j, q = l15
#pragma unroll
    for (int jb = 0; jb < 2; ++jb)
#pragma unroll
      for (int kg = 0; kg < 2; ++kg) {
        bf16x8 k0 = *(const bf16x8*)(Kt + koff[jb][kg][0]);
        bf16x8 k1 = *(const bf16x8*)(Kt + koff[jb][kg][1]);
#pragma unroll
        for (int hh = 0; hh < 2; ++hh) {
          f32x4 a = {};
          a = __builtin_amdgcn_mfma_f32_16x16x32_bf16(k0, Qf[hh][0], a, 0, 0, 0);
          a = __builtin_amdgcn_mfma_f32_16x16x32_bf16(k1, Qf[hh][1], a, 0, 0, 0);
          Tm[hh][jb][kg] = a;
        }
      }
    if (diag) {   // causal mask, global indices (covers partial + fully-masked)
      const int kvb = t * 64;
#pragma unroll
      for (int hh = 0; hh < 2; ++hh) {
        const int qg = qbase + hh * 16 + l15;
#pragma unroll
        for (int jb = 0; jb < 2; ++jb)
#pragma unroll
          for (int kg = 0; kg < 2; ++kg)
#pragma unroll
            for (int j = 0; j < 4; ++j)
              if (kvb + jb * 32 + l4 * 8 + kg * 4 + j > qg) Tm[hh][jb][kg][j] = -1e30f;
      }
    }
    // ---- P = exp2(T), trunc-packed into 16x16x32 A-operands (both halves) ----
    union { u32x4 u; bf16x8 v; } pa[2][2];   // [hh][jb]
#pragma unroll
    for (int hh = 0; hh < 2; ++hh)
#pragma unroll
      for (int jb = 0; jb < 2; ++jb) {
        u32x4 wds;
#pragma unroll
        for (int kg = 0; kg < 2; ++kg)
#pragma unroll
          for (int pr = 0; pr < 2; ++pr) {
            const unsigned int lo = fbits(__builtin_amdgcn_exp2f(Tm[hh][jb][kg][2 * pr]));
            const unsigned int hi = fbits(__builtin_amdgcn_exp2f(Tm[hh][jb][kg][2 * pr + 1]));
            wds[kg * 2 + pr] = (lo >> 16) | (hi & 0xFFFF0000u);   // trunc pack (P >= 0)
          }
        pa[hh][jb].u = wds;
      }
    // ---- PV: each V-frag read ONCE, feeds both halves ----
#pragma unroll
    for (int jb = 0; jb < 2; ++jb) {
      Ol2[0] = __builtin_amdgcn_mfma_f32_16x16x32_bf16(pa[0][jb].v, ones8, Ol2[0], 0, 0, 0);
      Ol2[1] = __builtin_amdgcn_mfma_f32_16x16x32_bf16(pa[1][jb].v, ones8, Ol2[1], 0, 0, 0);
#pragma unroll
      for (int vb = 0; vb < 4; ++vb) {
        bf16x8 vf = *(const bf16x8*)(Vv + voff[jb][vb]);
        O[0][vb] = __builtin_amdgcn_mfma_f32_16x16x32_bf16(pa[0][jb].v, vf, O[0][vb], 0, 0, 0);
        O[1][vb] = __builtin_amdgcn_mfma_f32_16x16x32_bf16(pa[1][jb].v, vf, O[1][vb], 0, 0, 0);
      }
    }
  };

  STAGE(0, 0);
  __syncthreads();

  int t = 0;
  while (t + 1 < nt) {                      // nt is even: loop covers all tiles
    STAGE(1, t + 1);
    if (t < myNt) COMPUTE(Ks[0], Vs[0], t);      // wave-uniform guard
    __syncthreads();
    if (t + 2 < nt) STAGE(0, t + 2);
    if (t + 1 < myNt) COMPUTE(Ks[1], Vs[1], t + 1);
    __syncthreads();
    t += 2;
  }

  // ---- normalize + store, per half ----
#pragma unroll
  for (int hh = 0; hh < 2; ++hh) {
    f32x4 linv;
#pragma unroll
    for (int j = 0; j < 4; ++j) linv[j] = 1.f / Ol2[hh][j];
#pragma unroll
    for (int vb = 0; vb < 4; ++vb) {
      const size_t base = (size_t)(b * SEQ + qbase + hh * 16) * 1024 + h * 64 + vb * 16 + l15;
      Oout[base + (size_t)(l4 * 4 + 0) * 1024] = f2bf(O[hh][vb][0] * linv[0]);
      Oout[base + (size_t)(l4 * 4 + 1) * 1024] = f2bf(O[hh][vb][1] * linv[1]);
      Oout[base + (size_t)(l4 * 4 + 2) * 1024] = f2bf(O[hh][vb][2] * linv[2]);
      Oout[base + (size_t)(l4 * 4 + 3) * 1024] = f2bf(O[hh][vb][3] * linv[3]);
    }
  }
}

// ---------- launcher ----------
extern "C" void kernel_launch(void* const* d_in, const int* in_sizes, int n_in,
                              void* d_out, int out_size, void* d_ws, size_t ws_size,
                              hipStream_t stream) {
  const float* x  = (const float*)d_in[0];
  const float* WQ = (const float*)d_in[1];
  const float* WK = (const float*)d_in[2];
  const float* WV = (const float*)d_in[3];
  const float* WO = (const float*)d_in[4];
  float* out = (float*)d_out;

  char* ws = (char*)d_ws;
  // ws layout (bytes), total 75.5 MB:
  //   QKb : 8192*2048*2 = 33554432
  //   Vtb : 1024*8192*2 = 16777216
  //   xb  : 8192*1024*2 = 16777216   (reused as attn output)
  //   Wqk : 2048*1024*2 =  4194304
  //   WVb : 1024*1024*2 =  2097152
  //   WOt : 1024*1024*2 =  2097152
  unsigned short* QKb = (unsigned short*)ws;
  unsigned short* Vtb = (unsigned short*)(ws + 33554432);
  unsigned short* xb  = (unsigned short*)(ws + 50331648);
  unsigned short* Wqk = (unsigned short*)(ws + 67108864);
  unsigned short* WVb = (unsigned short*)(ws + 71303168);
  unsigned short* WOt = (unsigned short*)(ws + 73400320);
  unsigned short* attnb = xb;   // xb consumed by both GEMMs before attn writes it

  const float c1s = 0.1803368801111204f;   // (1/sqrt(64)) * log2(e)

  // all fp32->bf16 converts in one launch
  cvt_fuse<<<15360, 256, 0, stream>>>(x, WQ, WK, WV, WO, xb, Wqk, WVb, WOt);

  // QK projection: [8192,1024] x [2048,1024]^T -> QKb [8192,2048] bf16
  // Q columns (<1024) pre-scaled by c1s.
  gemm_bt<true><<<(MROWS / 128) * (2048 / 128), 256, 0, stream>>>(
      xb, Wqk, QKb, MROWS, 2048, DMODEL, 2048, c1s, 1024);

  // V^T projection: WV [1024,1024] x xb[8192,1024]^T -> Vtb [1024,8192] bf16
  gemm_bt<true><<<(1024 / 128) * (MROWS / 128), 256, 0, stream>>>(
      WVb, xb, Vtb, 1024, MROWS, DMODEL, MROWS, 1.f, 0);

  // causal flash attention -> attnb [8192,1024] bf16  (BQ=128 blocks)
  attn_fwd<<<(SEQ / 128) * 64, 256, 0, stream>>>(QKb, Vtb, attnb);

  // output projection: [8192,1024] x [1024,1024]^T -> out [8192,1024] fp32
  gemm_bt<false><<<(MROWS / 128) * (DMODEL / 128), 256, 0, stream>>>(
      attnb, WOt, out, MROWS, DMODEL, DMODEL, DMODEL, 1.f, 0);
}

// Round 14
// 151.528 us; speedup vs baseline: 1.0366x; 1.0366x over previous
//
#include <hip/hip_runtime.h>
#include <hip/hip_bf16.h>
#include <stdint.h>
#include <stddef.h>

// ---------- types ----------
typedef __attribute__((ext_vector_type(8))) short bf16x8;   // 8 bf16 (4 VGPR)
typedef __attribute__((ext_vector_type(4))) short bf16x4;   // 4 bf16 (2 VGPR)
typedef __attribute__((ext_vector_type(4))) float f32x4;
typedef __attribute__((ext_vector_type(4))) unsigned short u16x4;
typedef __attribute__((ext_vector_type(4))) unsigned int u32x4;

#define DEVI static __device__ __forceinline__

// problem constants
static constexpr int BATCH = 4;
static constexpr int SEQ   = 2048;
static constexpr int DMODEL = 1024;
static constexpr int MROWS = BATCH * SEQ;          // 8192

DEVI unsigned short f2bf(float f) {
  union { float f; unsigned int u; } c; c.f = f;
  unsigned int u = c.u;
  unsigned int r = u + 0x7fffu + ((u >> 16) & 1u);   // RNE
  return (unsigned short)(r >> 16);
}

DEVI unsigned int fbits(float f) {
  union { float f; unsigned int u; } c; c.f = f;
  return c.u;
}

DEVI void gload_lds16(const void* g, void* l) {
  __builtin_amdgcn_global_load_lds(
      (const __attribute__((address_space(1))) void*)g,
      (__attribute__((address_space(3))) void*)l, 16, 0, 0);
}

// ---------- fused fp32 -> bf16 converts (one launch replaces five) ----------
__global__ void cvt_fuse(const float* __restrict__ x,  const float* __restrict__ WQ,
                         const float* __restrict__ WK, const float* __restrict__ WV,
                         const float* __restrict__ WO,
                         unsigned short* __restrict__ xb,
                         unsigned short* __restrict__ Wqk,
                         unsigned short* __restrict__ WVb,
                         unsigned short* __restrict__ WOt) {
  const int bid = blockIdx.x, tid = threadIdx.x;
  if (bid < 11264) {
    const float* src;
    unsigned short* dst;
    int i;
    if (bid < 8192)       { src = x;  dst = xb;            i = bid * 256 + tid; }
    else if (bid < 9216)  { src = WQ; dst = Wqk;           i = (bid - 8192) * 256 + tid; }
    else if (bid < 10240) { src = WK; dst = Wqk + 1048576; i = (bid - 9216) * 256 + tid; }
    else                  { src = WV; dst = WVb;           i = (bid - 10240) * 256 + tid; }
    f32x4 v = *(const f32x4*)(src + (size_t)i * 4);
    u16x4 o;
    o[0] = f2bf(v[0]); o[1] = f2bf(v[1]); o[2] = f2bf(v[2]); o[3] = f2bf(v[3]);
    *(u16x4*)(dst + (size_t)i * 4) = o;
  } else {
    const int i = (bid - 11264) * 256 + tid;     // 1M threads
    const int d = i >> 10, k = i & 1023;
    const int h = k >> 6, v = k & 63;
    WOt[i] = f2bf(WO[(size_t)(h * 1024 + d) * 64 + v]);
  }
}

// ---------- bf16 GEMM body (128x128 tile), single-barrier double-buffer ----------
// [verified] pre-swizzled gload_lds staging, XOR-swizzled LDS reads,
// epilogue col-scale. bid already XCD-swizzled by the caller.
template <bool OUTBF>
DEVI void gemm_body(const unsigned short* __restrict__ A,
                    const unsigned short* __restrict__ Bt,
                    void* __restrict__ Cv, int M, int N, int K, int ldc,
                    float cscale, int scale_cols, int bid,
                    unsigned short (*As)[128 * 64],
                    unsigned short (*Bs)[128 * 64]) {
  const int tid = threadIdx.x;
  const int lane = tid & 63;
  const int w = tid >> 6;
  const int wr = w >> 1, wc = w & 1;
  const int l15 = lane & 15, l4 = lane >> 4;
  const int nbn = N >> 7;
  const int mblk = bid / nbn, nblk = bid % nbn;
  const unsigned short* Ab = A + (size_t)mblk * 128 * K;
  const unsigned short* Bb = Bt + (size_t)nblk * 128 * K;
  f32x4 acc[4][4] = {};

  const int srow = tid >> 3;
  const int spos = tid & 7;
  const int nk = K >> 6;

  auto STAGE = [&](int buf, int t) {
    const int k0 = t * 64;
#pragma unroll
    for (int i = 0; i < 4; ++i) {
      const int row = srow + i * 32;
      const int sc = spos ^ (row & 7);
      gload_lds16(Ab + (size_t)row * K + k0 + sc * 8, (void*)(As[buf] + (tid + i * 256) * 8));
      gload_lds16(Bb + (size_t)row * K + k0 + sc * 8, (void*)(Bs[buf] + (tid + i * 256) * 8));
    }
  };

  auto COMPUTE = [&](const unsigned short* Asb, const unsigned short* Bsb) {
    bf16x8 af[2][4], bq[2][4];
#pragma unroll
    for (int cc = 0; cc < 2; ++cc) {
#pragma unroll
      for (int m = 0; m < 4; ++m) {
        const int ra = wr * 64 + m * 16 + l15;
        af[cc][m] = *(const bf16x8*)(Asb + ra * 64 + (((cc * 4 + l4) ^ (ra & 7)) * 8));
        const int rb = wc * 64 + m * 16 + l15;
        bq[cc][m] = *(const bf16x8*)(Bsb + rb * 64 + (((cc * 4 + l4) ^ (rb & 7)) * 8));
      }
    }
#pragma unroll
    for (int cc = 0; cc < 2; ++cc)
#pragma unroll
      for (int m = 0; m < 4; ++m)
#pragma unroll
        for (int n = 0; n < 4; ++n)
          acc[m][n] = __builtin_amdgcn_mfma_f32_16x16x32_bf16(af[cc][m], bq[cc][n], acc[m][n], 0, 0, 0);
  };

  STAGE(0, 0);
  __syncthreads();

  int t = 0;
  while (t + 1 < nk) {
    STAGE(1, t + 1);
    COMPUTE(As[0], Bs[0]);
    __syncthreads();
    if (t + 2 < nk) STAGE(0, t + 2);
    COMPUTE(As[1], Bs[1]);
    __syncthreads();
    t += 2;
  }
  if (t < nk) COMPUTE(As[0], Bs[0]);

#pragma unroll
  for (int m = 0; m < 4; ++m)
#pragma unroll
    for (int n = 0; n < 4; ++n) {
      int col = nblk * 128 + wc * 64 + n * 16 + l15;
      const float s = (col < scale_cols) ? cscale : 1.f;
#pragma unroll
      for (int j = 0; j < 4; ++j) {
        int row = mblk * 128 + wr * 64 + m * 16 + l4 * 4 + j;   // D: col=l&15, row=(l>>4)*4+j
        if (OUTBF)
          ((unsigned short*)Cv)[(size_t)row * ldc + col] = f2bf(acc[m][n][j] * s);
        else
          ((float*)Cv)[(size_t)row * ldc + col] = acc[m][n][j] * s;
      }
    }
}

// standalone GEMM (out-projection): internal bijective XCD swizzle
template <bool OUTBF>
__global__ __launch_bounds__(256)
void gemm_bt(const unsigned short* __restrict__ A,
             const unsigned short* __restrict__ Bt,
             void* __restrict__ Cv, int M, int N, int K, int ldc,
             float cscale, int scale_cols) {
  __shared__ unsigned short As[2][128 * 64];
  __shared__ unsigned short Bs[2][128 * 64];
  const int nwg = gridDim.x;
  const int bid = (blockIdx.x & 7) * (nwg >> 3) + (blockIdx.x >> 3);
  gemm_body<OUTBF>(A, Bt, Cv, M, N, K, ldc, cscale, scale_cols, bid, As, Bs);
}

// merged QK-projection + V^T-projection (independent, both read xb):
// blocks [0,1024)    : QK  tiles  (M=8192,N=2048, Q cols pre-scaled by c1s)
// blocks [1024,1536) : V^T tiles  (M=1024,N=8192)
// One dispatch removes the inter-kernel drain between the two GEMMs.
__global__ __launch_bounds__(256)
void gemm_qkv(const unsigned short* __restrict__ xb,
              const unsigned short* __restrict__ Wqk,
              unsigned short* __restrict__ QKb,
              const unsigned short* __restrict__ WVb,
              unsigned short* __restrict__ Vtb, float c1s) {
  __shared__ unsigned short As[2][128 * 64];
  __shared__ unsigned short Bs[2][128 * 64];
  if (blockIdx.x < 1024) {
    const int raw = blockIdx.x;
    const int bid = (raw & 7) * 128 + (raw >> 3);          // bijective over 1024
    gemm_body<true>(xb, Wqk, QKb, MROWS, 2048, DMODEL, 2048, c1s, 1024, bid, As, Bs);
  } else {
    const int raw = blockIdx.x - 1024;
    const int bid = (raw & 7) * 64 + (raw >> 3);           // bijective over 512
    gemm_body<true>(WVb, xb, Vtb, 1024, MROWS, DMODEL, MROWS, 1.f, 0, bid, As, Bs);
  }
}

// ---------- flash attention (causal), v10 [verified, 50.5 us] ----------
// Constant-shift softmax (P = exp2(T), no max tracking), ones-MFMA denominator,
// K=32 PV via row-permuted QK^T, hoisted LDS offsets, single-barrier dbuf.
__global__ __launch_bounds__(256, 5)
void attn_fwd(const unsigned short* __restrict__ QKb,
              const unsigned short* __restrict__ Vt,
              unsigned short* __restrict__ Oout) {
  __shared__ unsigned short Ks[2][64 * 64];
  __shared__ unsigned short Vs[2][64 * 64];
  const int bid = blockIdx.x;
  const int qi = 31 - (bid >> 6);          // reversed: heavy blocks dispatch first
  const int bh = bid & 63;
  const int b = bh >> 4, h = bh & 15;
  const int tid = threadIdx.x, lane = tid & 63, w = tid >> 6;
  const int l15 = lane & 15, l4 = lane >> 4;
  const int qbase = qi * 64 + w * 16;
  const int LDQ = 2048;

  const size_t qrow = (size_t)(b * SEQ + qbase + l15) * LDQ + h * 64;
  const bf16x8 Qf0 = *(const bf16x8*)(QKb + qrow + l4 * 8);
  const bf16x8 Qf1 = *(const bf16x8*)(QKb + qrow + 32 + l4 * 8);

  const unsigned short* Kbase = QKb + (size_t)b * SEQ * LDQ + 1024 + h * 64;
  const unsigned short* Vbase = Vt + (size_t)(h * 64) * MROWS + (size_t)b * SEQ;

  f32x4 O[4] = {};
  f32x4 Ol = {};                               // per-q-row sum of P (denominator)
  const int nt = qi + 1;                       // same tile count for all 4 waves

  // ---- hoisted LDS offsets ----
  int koff[2][2][2];   // [jb][hh][cc]; K rows r = jb*32 + (l15>>2)*8 + hh*4 + (l15&3)
#pragma unroll
  for (int jb = 0; jb < 2; ++jb)
#pragma unroll
    for (int hh = 0; hh < 2; ++hh) {
      const int r = jb * 32 + (l15 >> 2) * 8 + hh * 4 + (l15 & 3);
      const int fk = ((r & 7) + ((r >> 3) & 1) * 4) & 7;
#pragma unroll
      for (int cc = 0; cc < 2; ++cc)
        koff[jb][hh][cc] = r * 64 + (((cc * 4 + l4) ^ fk) * 8);
    }
  int voff[2][4];      // [jb][vb] (b128 V reads)
#pragma unroll
  for (int jb = 0; jb < 2; ++jb)
#pragma unroll
    for (int vb = 0; vb < 4; ++vb) {
      const int vr = vb * 16 + l15;
      voff[jb][vb] = vr * 64 + (((4 * jb + l4) ^ (vr & 7)) * 8);
    }

  const int srow = tid >> 3, spos = tid & 7;
  const int fkS = (((srow & 7) + ((srow >> 3) & 1) * 4) & 7);
  const int scK = (spos ^ fkS) * 8;
  const int scV = (spos ^ (srow & 7)) * 8;
  const unsigned short* KsrcA = Kbase + (size_t)srow * LDQ + scK;
  const unsigned short* KsrcB = Kbase + (size_t)(srow + 32) * LDQ + scK;
  const unsigned short* VsrcA = Vbase + (size_t)srow * MROWS + scV;
  const unsigned short* VsrcB = Vbase + (size_t)(srow + 32) * MROWS + scV;

  auto STAGE = [&](int buf, int t) {
    const int kv0 = t * 64;
    gload_lds16(KsrcA + (size_t)kv0 * LDQ, (void*)(Ks[buf] + tid * 8));
    gload_lds16(KsrcB + (size_t)kv0 * LDQ, (void*)(Ks[buf] + (tid + 256) * 8));
    gload_lds16(VsrcA + kv0, (void*)(Vs[buf] + tid * 8));
    gload_lds16(VsrcB + kv0, (void*)(Vs[buf] + (tid + 256) * 8));
  };

  const bf16x8 ones8 = { (short)0x3F80, (short)0x3F80, (short)0x3F80, (short)0x3F80,
                         (short)0x3F80, (short)0x3F80, (short)0x3F80, (short)0x3F80 };

  auto COMPUTE = [&](const unsigned short* Kt, const unsigned short* Vv, int t) {
    const bool last = (t == nt - 1);
    f32x4 Tm[2][2];
#pragma unroll
    for (int jb = 0; jb < 2; ++jb)
#pragma unroll
      for (int hh = 0; hh < 2; ++hh) {
        bf16x8 k0 = *(const bf16x8*)(Kt + koff[jb][hh][0]);
        bf16x8 k1 = *(const bf16x8*)(Kt + koff[jb][hh][1]);
        f32x4 a = {};
        a = __builtin_amdgcn_mfma_f32_16x16x32_bf16(k0, Qf0, a, 0, 0, 0);
        a = __builtin_amdgcn_mfma_f32_16x16x32_bf16(k1, Qf1, a, 0, 0, 0);
        Tm[jb][hh] = a;
      }
    if (last) {   // universal causal mask: kv_local > q_local
      const int ql = w * 16 + l15;
#pragma unroll
      for (int jb = 0; jb < 2; ++jb)
#pragma unroll
        for (int hh = 0; hh < 2; ++hh)
#pragma unroll
          for (int j = 0; j < 4; ++j)
            if (jb * 32 + l4 * 8 + hh * 4 + j > ql) Tm[jb][hh][j] = -1e30f;
    }
#pragma unroll
    for (int jb = 0; jb < 2; ++jb) {
      u32x4 wds;
#pragma unroll
      for (int hh = 0; hh < 2; ++hh)
#pragma unroll
        for (int pr = 0; pr < 2; ++pr) {
          const unsigned int lo = fbits(__builtin_amdgcn_exp2f(Tm[jb][hh][2 * pr]));
          const unsigned int hi = fbits(__builtin_amdgcn_exp2f(Tm[jb][hh][2 * pr + 1]));
          wds[hh * 2 + pr] = (lo >> 16) | (hi & 0xFFFF0000u);   // trunc pack (P >= 0)
        }
      union { u32x4 u; bf16x8 v; } pa; pa.u = wds;
      Ol = __builtin_amdgcn_mfma_f32_16x16x32_bf16(pa.v, ones8, Ol, 0, 0, 0);
#pragma unroll
      for (int vb = 0; vb < 4; ++vb) {
        bf16x8 vf = *(const bf16x8*)(Vv + voff[jb][vb]);
        O[vb] = __builtin_amdgcn_mfma_f32_16x16x32_bf16(pa.v, vf, O[vb], 0, 0, 0);
      }
    }
  };

  STAGE(0, 0);
  __syncthreads();

  int t = 0;
  while (t + 1 < nt) {
    STAGE(1, t + 1);
    COMPUTE(Ks[0], Vs[0], t);
    __syncthreads();
    if (t + 2 < nt) STAGE(0, t + 2);
    COMPUTE(Ks[1], Vs[1], t + 1);
    __syncthreads();
    t += 2;
  }
  if (t < nt) COMPUTE(Ks[0], Vs[0], t);

  f32x4 linv;
#pragma unroll
  for (int j = 0; j < 4; ++j) linv[j] = 1.f / Ol[j];
#pragma unroll
  for (int vb = 0; vb < 4; ++vb) {
    const size_t base = (size_t)(b * SEQ + qbase) * 1024 + h * 64 + vb * 16 + l15;
    Oout[base + (size_t)(l4 * 4 + 0) * 1024] = f2bf(O[vb][0] * linv[0]);
    Oout[base + (size_t)(l4 * 4 + 1) * 1024] = f2bf(O[vb][1] * linv[1]);
    Oout[base + (size_t)(l4 * 4 + 2) * 1024] = f2bf(O[vb][2] * linv[2]);
    Oout[base + (size_t)(l4 * 4 + 3) * 1024] = f2bf(O[vb][3] * linv[3]);
  }
}

// ---------- launcher ----------
extern "C" void kernel_launch(void* const* d_in, const int* in_sizes, int n_in,
                              void* d_out, int out_size, void* d_ws, size_t ws_size,
                              hipStream_t stream) {
  const float* x  = (const float*)d_in[0];
  const float* WQ = (const float*)d_in[1];
  const float* WK = (const float*)d_in[2];
  const float* WV = (const float*)d_in[3];
  const float* WO = (const float*)d_in[4];
  float* out = (float*)d_out;

  char* ws = (char*)d_ws;
  // ws layout (bytes), total 75.5 MB:
  //   QKb : 8192*2048*2 = 33554432
  //   Vtb : 1024*8192*2 = 16777216
  //   xb  : 8192*1024*2 = 16777216   (reused as attn output)
  //   Wqk : 2048*1024*2 =  4194304
  //   WVb : 1024*1024*2 =  2097152
  //   WOt : 1024*1024*2 =  2097152
  unsigned short* QKb = (unsigned short*)ws;
  unsigned short* Vtb = (unsigned short*)(ws + 33554432);
  unsigned short* xb  = (unsigned short*)(ws + 50331648);
  unsigned short* Wqk = (unsigned short*)(ws + 67108864);
  unsigned short* WVb = (unsigned short*)(ws + 71303168);
  unsigned short* WOt = (unsigned short*)(ws + 73400320);
  unsigned short* attnb = xb;   // xb consumed by both GEMMs before attn writes it

  const float c1s = 0.1803368801111204f;   // (1/sqrt(64)) * log2(e)

  // all fp32->bf16 converts in one launch
  cvt_fuse<<<15360, 256, 0, stream>>>(x, WQ, WK, WV, WO, xb, Wqk, WVb, WOt);

  // merged QK projection + V^T projection (independent, both read xb)
  gemm_qkv<<<1536, 256, 0, stream>>>(xb, Wqk, QKb, WVb, Vtb, c1s);

  // causal flash attention -> attnb [8192,1024] bf16
  attn_fwd<<<(SEQ / 64) * 64, 256, 0, stream>>>(QKb, Vtb, attnb);

  // output projection: [8192,1024] x [1024,1024]^T -> out [8192,1024] fp32
  gemm_bt<false><<<(MROWS / 128) * (DMODEL / 128), 256, 0, stream>>>(
      attnb, WOt, out, MROWS, DMODEL, DMODEL, DMODEL, 1.f, 0);
}

// Round 15
// 146.902 us; speedup vs baseline: 1.0692x; 1.0315x over previous
//
#include <hip/hip_runtime.h>
#include <hip/hip_bf16.h>
#include <stdint.h>
#include <stddef.h>

// ---------- types ----------
typedef __attribute__((ext_vector_type(8))) short bf16x8;   // 8 bf16 (4 VGPR)
typedef __attribute__((ext_vector_type(4))) short bf16x4;   // 4 bf16 (2 VGPR)
typedef __attribute__((ext_vector_type(4))) float f32x4;
typedef __attribute__((ext_vector_type(4))) unsigned short u16x4;
typedef __attribute__((ext_vector_type(4))) unsigned int u32x4;

#define DEVI static __device__ __forceinline__

// problem constants
static constexpr int BATCH = 4;
static constexpr int SEQ   = 2048;
static constexpr int DMODEL = 1024;
static constexpr int MROWS = BATCH * SEQ;          // 8192

DEVI unsigned short f2bf(float f) {
  union { float f; unsigned int u; } c; c.f = f;
  unsigned int u = c.u;
  unsigned int r = u + 0x7fffu + ((u >> 16) & 1u);   // RNE
  return (unsigned short)(r >> 16);
}

DEVI unsigned int fbits(float f) {
  union { float f; unsigned int u; } c; c.f = f;
  return c.u;
}

DEVI void gload_lds16(const void* g, void* l) {
  __builtin_amdgcn_global_load_lds(
      (const __attribute__((address_space(1))) void*)g,
      (__attribute__((address_space(3))) void*)l, 16, 0, 0);
}

// ---------- fused fp32 -> bf16 converts (one launch replaces five) ----------
__global__ void cvt_fuse(const float* __restrict__ x,  const float* __restrict__ WQ,
                         const float* __restrict__ WK, const float* __restrict__ WV,
                         const float* __restrict__ WO,
                         unsigned short* __restrict__ xb,
                         unsigned short* __restrict__ Wqk,
                         unsigned short* __restrict__ WVb,
                         unsigned short* __restrict__ WOt) {
  const int bid = blockIdx.x, tid = threadIdx.x;
  if (bid < 11264) {
    const float* src;
    unsigned short* dst;
    int i;
    if (bid < 8192)       { src = x;  dst = xb;            i = bid * 256 + tid; }
    else if (bid < 9216)  { src = WQ; dst = Wqk;           i = (bid - 8192) * 256 + tid; }
    else if (bid < 10240) { src = WK; dst = Wqk + 1048576; i = (bid - 9216) * 256 + tid; }
    else                  { src = WV; dst = WVb;           i = (bid - 10240) * 256 + tid; }
    f32x4 v = *(const f32x4*)(src + (size_t)i * 4);
    u16x4 o;
    o[0] = f2bf(v[0]); o[1] = f2bf(v[1]); o[2] = f2bf(v[2]); o[3] = f2bf(v[3]);
    *(u16x4*)(dst + (size_t)i * 4) = o;
  } else {
    const int i = (bid - 11264) * 256 + tid;     // 1M threads
    const int d = i >> 10, k = i & 1023;
    const int h = k >> 6, v = k & 63;
    WOt[i] = f2bf(WO[(size_t)(h * 1024 + d) * 64 + v]);
  }
}

// ---------- bf16 GEMM (128x128 tile), single-barrier double-buffer [verified] ----------
template <bool OUTBF>
__global__ __launch_bounds__(256)
void gemm_bt(const unsigned short* __restrict__ A,
             const unsigned short* __restrict__ Bt,
             void* __restrict__ Cv, int M, int N, int K, int ldc,
             float cscale, int scale_cols) {
  __shared__ unsigned short As[2][128 * 64];
  __shared__ unsigned short Bs[2][128 * 64];
  const int tid = threadIdx.x;
  const int lane = tid & 63;
  const int w = tid >> 6;
  const int wr = w >> 1, wc = w & 1;
  const int l15 = lane & 15, l4 = lane >> 4;
  const int nbn = N >> 7;
  const int nwg = gridDim.x;
  const int bid = (blockIdx.x & 7) * (nwg >> 3) + (blockIdx.x >> 3);
  const int mblk = bid / nbn, nblk = bid % nbn;
  const unsigned short* Ab = A + (size_t)mblk * 128 * K;
  const unsigned short* Bb = Bt + (size_t)nblk * 128 * K;
  f32x4 acc[4][4] = {};

  const int srow = tid >> 3;
  const int spos = tid & 7;
  const int nk = K >> 6;

  auto STAGE = [&](int buf, int t) {
    const int k0 = t * 64;
#pragma unroll
    for (int i = 0; i < 4; ++i) {
      const int row = srow + i * 32;
      const int sc = spos ^ (row & 7);
      gload_lds16(Ab + (size_t)row * K + k0 + sc * 8, (void*)(As[buf] + (tid + i * 256) * 8));
      gload_lds16(Bb + (size_t)row * K + k0 + sc * 8, (void*)(Bs[buf] + (tid + i * 256) * 8));
    }
  };

  auto COMPUTE = [&](const unsigned short* Asb, const unsigned short* Bsb) {
    bf16x8 af[2][4], bq[2][4];
#pragma unroll
    for (int cc = 0; cc < 2; ++cc) {
#pragma unroll
      for (int m = 0; m < 4; ++m) {
        const int ra = wr * 64 + m * 16 + l15;
        af[cc][m] = *(const bf16x8*)(Asb + ra * 64 + (((cc * 4 + l4) ^ (ra & 7)) * 8));
        const int rb = wc * 64 + m * 16 + l15;
        bq[cc][m] = *(const bf16x8*)(Bsb + rb * 64 + (((cc * 4 + l4) ^ (rb & 7)) * 8));
      }
    }
#pragma unroll
    for (int cc = 0; cc < 2; ++cc)
#pragma unroll
      for (int m = 0; m < 4; ++m)
#pragma unroll
        for (int n = 0; n < 4; ++n)
          acc[m][n] = __builtin_amdgcn_mfma_f32_16x16x32_bf16(af[cc][m], bq[cc][n], acc[m][n], 0, 0, 0);
  };

  STAGE(0, 0);
  __syncthreads();

  int t = 0;
  while (t + 1 < nk) {
    STAGE(1, t + 1);
    COMPUTE(As[0], Bs[0]);
    __syncthreads();
    if (t + 2 < nk) STAGE(0, t + 2);
    COMPUTE(As[1], Bs[1]);
    __syncthreads();
    t += 2;
  }
  if (t < nk) COMPUTE(As[0], Bs[0]);

#pragma unroll
  for (int m = 0; m < 4; ++m)
#pragma unroll
    for (int n = 0; n < 4; ++n) {
      int col = nblk * 128 + wc * 64 + n * 16 + l15;
      const float s = (col < scale_cols) ? cscale : 1.f;
#pragma unroll
      for (int j = 0; j < 4; ++j) {
        int row = mblk * 128 + wr * 64 + m * 16 + l4 * 4 + j;
        if (OUTBF)
          ((unsigned short*)Cv)[(size_t)row * ldc + col] = f2bf(acc[m][n][j] * s);
        else
          ((float*)Cv)[(size_t)row * ldc + col] = acc[m][n][j] * s;
      }
    }
}

// ---------- bf16 GEMM (256x256 tile, 8-phase counted-vmcnt schedule) ----------
// m201-template port. 8 waves (2M x 4N), wave out 128x64 (acc[8][4]), BK=64.
// LDS 128 KB: As[2][256x64] + Bs[2][256x64]; buffer = tile parity.
// Half-tile = 128 rows x 64 K (16 KB) = 2 gload_lds16 per thread.
// Per phase: {ds-read subtile, stage half-tile(s), barrier, lgkmcnt(0),
//   setprio(1) 16 MFMA setprio(0), barrier}. vmcnt(4) ONLY at p1/p5.
// Staging schedule (iteration computes T=buf0 p1-4, T+1=buf1 p5-8):
//   p1: A0(T+1)->buf1   [buf1.A reads ended prev p8]
//   p2: A1(T+1)->buf1, B0(T+2)->buf0   [buf0.B in regs after p1]
//   p3: B1(T+2)->buf0
//   p5: A0(T+2)->buf0   [buf0.A reads ended p4]
//   p6: A1(T+2)->buf0
//   p7: B0(T+3)->buf1   [buf1.B in regs after p5]
//   p8: B1(T+3)->buf1
// Outstanding-count: exactly 12 at each wait point, oldest 8 = the data the
// next 4 phases need -> vmcnt(4) at p1 and p5 (verified for prologue/steady/tail).
#define MFMA_(a, b, c) __builtin_amdgcn_mfma_f32_16x16x32_bf16(a, b, c, 0, 0, 0)
#define PH(P, MQ, READB, ...) do {                                            \
  const unsigned short* As_ = As[P] + aoA + (2 * (MQ)) * 1024;                \
  const unsigned short* Bs_ = Bs[P] + boB;                                    \
  if (READB) {                                                                \
    _Pragma("unroll")                                                         \
    for (int n = 0; n < 4; ++n) {                                             \
      bq[n][0] = *(const bf16x8*)(Bs_ + n * 1024 + ax0);                      \
      bq[n][1] = *(const bf16x8*)(Bs_ + n * 1024 + ax1);                      \
    }                                                                         \
  }                                                                           \
  bf16x8 a00 = *(const bf16x8*)(As_ + ax0);                                   \
  bf16x8 a01 = *(const bf16x8*)(As_ + ax1);                                   \
  bf16x8 a10 = *(const bf16x8*)(As_ + 1024 + ax0);                            \
  bf16x8 a11 = *(const bf16x8*)(As_ + 1024 + ax1);                            \
  __VA_ARGS__;                                                                \
  __builtin_amdgcn_sched_barrier(0);                                          \
  __builtin_amdgcn_s_barrier();                                               \
  asm volatile("s_waitcnt lgkmcnt(0)" ::: "memory");                          \
  __builtin_amdgcn_sched_barrier(0);                                          \
  __builtin_amdgcn_s_setprio(1);                                              \
  _Pragma("unroll")                                                           \
  for (int n = 0; n < 4; ++n) {                                               \
    acc[2 * (MQ)][n]     = MFMA_(a00, bq[n][0], acc[2 * (MQ)][n]);            \
    acc[2 * (MQ)][n]     = MFMA_(a01, bq[n][1], acc[2 * (MQ)][n]);            \
    acc[2 * (MQ) + 1][n] = MFMA_(a10, bq[n][0], acc[2 * (MQ) + 1][n]);        \
    acc[2 * (MQ) + 1][n] = MFMA_(a11, bq[n][1], acc[2 * (MQ) + 1][n]);        \
  }                                                                           \
  __builtin_amdgcn_s_setprio(0);                                              \
  __builtin_amdgcn_sched_barrier(0);                                          \
  __builtin_amdgcn_s_barrier();                                               \
  __builtin_amdgcn_sched_barrier(0);                                          \
} while (0)

__global__ __launch_bounds__(512, 1)
void gemm256(const unsigned short* __restrict__ A,
             const unsigned short* __restrict__ Bt,
             unsigned short* __restrict__ C, int M, int N, int K, int ldc,
             float cscale, int scale_cols) {
  __shared__ unsigned short As[2][256 * 64];
  __shared__ unsigned short Bs[2][256 * 64];
  const int tid = threadIdx.x, lane = tid & 63, w = tid >> 6;
  const int wm = w >> 2, wn = w & 3;
  const int l15 = lane & 15, l4 = lane >> 4;
  const int nbn = N >> 8;
  const int bid = (blockIdx.x & 7) * (gridDim.x >> 3) + (blockIdx.x >> 3);
  const int mblk = bid / nbn, nblk = bid % nbn;
  const unsigned short* Ab = A + (size_t)mblk * 256 * K;
  const unsigned short* Bb = Bt + (size_t)nblk * 256 * K;
  f32x4 acc[8][4] = {};
  bf16x8 bq[4][2];
  const int nk = K >> 6;

  // LDS read bases (swizzle xor = l15&7 since tile-row % 8 == l15 % 8)
  const int aoA = wm * 8192 + l15 * 64;
  const int boB = (wn >> 1) * 8192 + (wn & 1) * 4096 + l15 * 64;
  const int ax0 = ((l4 ^ (l15 & 7)) * 8);
  const int ax1 = (((4 + l4) ^ (l15 & 7)) * 8);

  // staging: half-tile = 128 rows x 64 K; thread covers chunks tid, tid+512
  const int c1r = tid >> 3;                       // rows 0..63
  const int s1 = ((tid & 7) ^ (c1r & 7)) * 8;     // same xor for row c1r+64
  auto SA = [&](int p, int kt, int h) {
    unsigned short* dst = As[p] + h * 8192 + tid * 8;
    const unsigned short* src = Ab + (size_t)(h * 128 + c1r) * K + kt * 64 + s1;
    gload_lds16(src, dst);
    gload_lds16(src + (size_t)64 * K, dst + 4096);
  };
  auto SB = [&](int p, int kt, int h) {
    unsigned short* dst = Bs[p] + h * 8192 + tid * 8;
    const unsigned short* src = Bb + (size_t)(h * 128 + c1r) * K + kt * 64 + s1;
    gload_lds16(src, dst);
    gload_lds16(src + (size_t)64 * K, dst + 4096);
  };

  // prologue: B(0), A(0), B(1) = 12 loads; wait oldest 8 (= tile 0) landed
  SB(0, 0, 0); SB(0, 0, 1); SA(0, 0, 0); SA(0, 0, 1); SB(1, 1, 0); SB(1, 1, 1);
  asm volatile("s_waitcnt vmcnt(4)" ::: "memory");
  __builtin_amdgcn_sched_barrier(0);
  __builtin_amdgcn_s_barrier();
  __builtin_amdgcn_sched_barrier(0);

  for (int i = 0; i < (nk >> 1); ++i) {
    const int T = 2 * i;
    // p1..p4: compute tile T from buf0
    asm volatile("s_waitcnt vmcnt(4)" ::: "memory");
    __builtin_amdgcn_sched_barrier(0);
    PH(0, 0, true,  { if (T + 1 < nk) SA(1, T + 1, 0); });
    PH(0, 1, false, { if (T + 1 < nk) SA(1, T + 1, 1); if (T + 2 < nk) SB(0, T + 2, 0); });
    PH(0, 2, false, { if (T + 2 < nk) SB(0, T + 2, 1); });
    PH(0, 3, false, {});
    // p5..p8: compute tile T+1 from buf1
    asm volatile("s_waitcnt vmcnt(4)" ::: "memory");
    __builtin_amdgcn_sched_barrier(0);
    PH(1, 0, true,  { if (T + 2 < nk) SA(0, T + 2, 0); });
    PH(1, 1, false, { if (T + 2 < nk) SA(0, T + 2, 1); });
    PH(1, 2, false, { if (T + 3 < nk) SB(1, T + 3, 0); });
    PH(1, 3, false, { if (T + 3 < nk) SB(1, T + 3, 1); });
  }

  // epilogue: D col=l15 (B row), row=(l>>4)*4+j (A row)
#pragma unroll
  for (int m = 0; m < 8; ++m)
#pragma unroll
    for (int n = 0; n < 4; ++n) {
      int col = nblk * 256 + wn * 64 + n * 16 + l15;
      const float s = (col < scale_cols) ? cscale : 1.f;
#pragma unroll
      for (int j = 0; j < 4; ++j) {
        int row = mblk * 256 + wm * 128 + m * 16 + l4 * 4 + j;
        C[(size_t)row * ldc + col] = f2bf(acc[m][n][j] * s);
      }
    }
}
#undef PH
#undef MFMA_

// ---------- flash attention (causal), v10 [verified, 50.5 us] ----------
__global__ __launch_bounds__(256, 5)
void attn_fwd(const unsigned short* __restrict__ QKb,
              const unsigned short* __restrict__ Vt,
              unsigned short* __restrict__ Oout) {
  __shared__ unsigned short Ks[2][64 * 64];
  __shared__ unsigned short Vs[2][64 * 64];
  const int bid = blockIdx.x;
  const int qi = 31 - (bid >> 6);          // reversed: heavy blocks dispatch first
  const int bh = bid & 63;
  const int b = bh >> 4, h = bh & 15;
  const int tid = threadIdx.x, lane = tid & 63, w = tid >> 6;
  const int l15 = lane & 15, l4 = lane >> 4;
  const int qbase = qi * 64 + w * 16;
  const int LDQ = 2048;

  const size_t qrow = (size_t)(b * SEQ + qbase + l15) * LDQ + h * 64;
  const bf16x8 Qf0 = *(const bf16x8*)(QKb + qrow + l4 * 8);
  const bf16x8 Qf1 = *(const bf16x8*)(QKb + qrow + 32 + l4 * 8);

  const unsigned short* Kbase = QKb + (size_t)b * SEQ * LDQ + 1024 + h * 64;
  const unsigned short* Vbase = Vt + (size_t)(h * 64) * MROWS + (size_t)b * SEQ;

  f32x4 O[4] = {};
  f32x4 Ol = {};                               // per-q-row sum of P (denominator)
  const int nt = qi + 1;                       // same tile count for all 4 waves

  int koff[2][2][2];   // [jb][hh][cc]; K rows r = jb*32 + (l15>>2)*8 + hh*4 + (l15&3)
#pragma unroll
  for (int jb = 0; jb < 2; ++jb)
#pragma unroll
    for (int hh = 0; hh < 2; ++hh) {
      const int r = jb * 32 + (l15 >> 2) * 8 + hh * 4 + (l15 & 3);
      const int fk = ((r & 7) + ((r >> 3) & 1) * 4) & 7;
#pragma unroll
      for (int cc = 0; cc < 2; ++cc)
        koff[jb][hh][cc] = r * 64 + (((cc * 4 + l4) ^ fk) * 8);
    }
  int voff[2][4];      // [jb][vb] (b128 V reads)
#pragma unroll
  for (int jb = 0; jb < 2; ++jb)
#pragma unroll
    for (int vb = 0; vb < 4; ++vb) {
      const int vr = vb * 16 + l15;
      voff[jb][vb] = vr * 64 + (((4 * jb + l4) ^ (vr & 7)) * 8);
    }

  const int srow = tid >> 3, spos = tid & 7;
  const int fkS = (((srow & 7) + ((srow >> 3) & 1) * 4) & 7);
  const int scK = (spos ^ fkS) * 8;
  const int scV = (spos ^ (srow & 7)) * 8;
  const unsigned short* KsrcA = Kbase + (size_t)srow * LDQ + scK;
  const unsigned short* KsrcB = Kbase + (size_t)(srow + 32) * LDQ + scK;
  const unsigned short* VsrcA = Vbase + (size_t)srow * MROWS + scV;
  const unsigned short* VsrcB = Vbase + (size_t)(srow + 32) * MROWS + scV;

  auto STAGE = [&](int buf, int t) {
    const int kv0 = t * 64;
    gload_lds16(KsrcA + (size_t)kv0 * LDQ, (void*)(Ks[buf] + tid * 8));
    gload_lds16(KsrcB + (size_t)kv0 * LDQ, (void*)(Ks[buf] + (tid + 256) * 8));
    gload_lds16(VsrcA + kv0, (void*)(Vs[buf] + tid * 8));
    gload_lds16(VsrcB + kv0, (void*)(Vs[buf] + (tid + 256) * 8));
  };

  const bf16x8 ones8 = { (short)0x3F80, (short)0x3F80, (short)0x3F80, (short)0x3F80,
                         (short)0x3F80, (short)0x3F80, (short)0x3F80, (short)0x3F80 };

  auto COMPUTE = [&](const unsigned short* Kt, const unsigned short* Vv, int t) {
    const bool last = (t == nt - 1);
    f32x4 Tm[2][2];
#pragma unroll
    for (int jb = 0; jb < 2; ++jb)
#pragma unroll
      for (int hh = 0; hh < 2; ++hh) {
        bf16x8 k0 = *(const bf16x8*)(Kt + koff[jb][hh][0]);
        bf16x8 k1 = *(const bf16x8*)(Kt + koff[jb][hh][1]);
        f32x4 a = {};
        a = __builtin_amdgcn_mfma_f32_16x16x32_bf16(k0, Qf0, a, 0, 0, 0);
        a = __builtin_amdgcn_mfma_f32_16x16x32_bf16(k1, Qf1, a, 0, 0, 0);
        Tm[jb][hh] = a;
      }
    if (last) {   // universal causal mask: kv_local > q_local
      const int ql = w * 16 + l15;
#pragma unroll
      for (int jb = 0; jb < 2; ++jb)
#pragma unroll
        for (int hh = 0; hh < 2; ++hh)
#pragma unroll
          for (int j = 0; j < 4; ++j)
            if (jb * 32 + l4 * 8 + hh * 4 + j > ql) Tm[jb][hh][j] = -1e30f;
    }
#pragma unroll
    for (int jb = 0; jb < 2; ++jb) {
      u32x4 wds;
#pragma unroll
      for (int hh = 0; hh < 2; ++hh)
#pragma unroll
        for (int pr = 0; pr < 2; ++pr) {
          const unsigned int lo = fbits(__builtin_amdgcn_exp2f(Tm[jb][hh][2 * pr]));
          const unsigned int hi = fbits(__builtin_amdgcn_exp2f(Tm[jb][hh][2 * pr + 1]));
          wds[hh * 2 + pr] = (lo >> 16) | (hi & 0xFFFF0000u);   // trunc pack (P >= 0)
        }
      union { u32x4 u; bf16x8 v; } pa; pa.u = wds;
      Ol = __builtin_amdgcn_mfma_f32_16x16x32_bf16(pa.v, ones8, Ol, 0, 0, 0);
#pragma unroll
      for (int vb = 0; vb < 4; ++vb) {
        bf16x8 vf = *(const bf16x8*)(Vv + voff[jb][vb]);
        O[vb] = __builtin_amdgcn_mfma_f32_16x16x32_bf16(pa.v, vf, O[vb], 0, 0, 0);
      }
    }
  };

  STAGE(0, 0);
  __syncthreads();

  int t = 0;
  while (t + 1 < nt) {
    STAGE(1, t + 1);
    COMPUTE(Ks[0], Vs[0], t);
    __syncthreads();
    if (t + 2 < nt) STAGE(0, t + 2);
    COMPUTE(Ks[1], Vs[1], t + 1);
    __syncthreads();
    t += 2;
  }
  if (t < nt) COMPUTE(Ks[0], Vs[0], t);

  f32x4 linv;
#pragma unroll
  for (int j = 0; j < 4; ++j) linv[j] = 1.f / Ol[j];
#pragma unroll
  for (int vb = 0; vb < 4; ++vb) {
    const size_t base = (size_t)(b * SEQ + qbase) * 1024 + h * 64 + vb * 16 + l15;
    Oout[base + (size_t)(l4 * 4 + 0) * 1024] = f2bf(O[vb][0] * linv[0]);
    Oout[base + (size_t)(l4 * 4 + 1) * 1024] = f2bf(O[vb][1] * linv[1]);
    Oout[base + (size_t)(l4 * 4 + 2) * 1024] = f2bf(O[vb][2] * linv[2]);
    Oout[base + (size_t)(l4 * 4 + 3) * 1024] = f2bf(O[vb][3] * linv[3]);
  }
}

// ---------- launcher ----------
extern "C" void kernel_launch(void* const* d_in, const int* in_sizes, int n_in,
                              void* d_out, int out_size, void* d_ws, size_t ws_size,
                              hipStream_t stream) {
  const float* x  = (const float*)d_in[0];
  const float* WQ = (const float*)d_in[1];
  const float* WK = (const float*)d_in[2];
  const float* WV = (const float*)d_in[3];
  const float* WO = (const float*)d_in[4];
  float* out = (float*)d_out;

  char* ws = (char*)d_ws;
  // ws layout (bytes), total 75.5 MB:
  //   QKb : 8192*2048*2 = 33554432
  //   Vtb : 1024*8192*2 = 16777216
  //   xb  : 8192*1024*2 = 16777216   (reused as attn output)
  //   Wqk : 2048*1024*2 =  4194304
  //   WVb : 1024*1024*2 =  2097152
  //   WOt : 1024*1024*2 =  2097152
  unsigned short* QKb = (unsigned short*)ws;
  unsigned short* Vtb = (unsigned short*)(ws + 33554432);
  unsigned short* xb  = (unsigned short*)(ws + 50331648);
  unsigned short* Wqk = (unsigned short*)(ws + 67108864);
  unsigned short* WVb = (unsigned short*)(ws + 71303168);
  unsigned short* WOt = (unsigned short*)(ws + 73400320);
  unsigned short* attnb = xb;   // xb consumed by both GEMMs before attn writes it

  const float c1s = 0.1803368801111204f;   // (1/sqrt(64)) * log2(e)

  // all fp32->bf16 converts in one launch
  cvt_fuse<<<15360, 256, 0, stream>>>(x, WQ, WK, WV, WO, xb, Wqk, WVb, WOt);

  // QK projection (256^2 8-phase): [8192,1024] x [2048,1024]^T -> QKb bf16
  // Q columns (<1024) pre-scaled by c1s. Grid 32x8 = 256 blocks = 1/CU.
  gemm256<<<(MROWS / 256) * (2048 / 256), 512, 0, stream>>>(
      xb, Wqk, QKb, MROWS, 2048, DMODEL, 2048, c1s, 1024);

  // V^T projection: WV [1024,1024] x xb[8192,1024]^T -> Vtb [1024,8192] bf16
  gemm_bt<true><<<(1024 / 128) * (MROWS / 128), 256, 0, stream>>>(
      WVb, xb, Vtb, 1024, MROWS, DMODEL, MROWS, 1.f, 0);

  // causal flash attention -> attnb [8192,1024] bf16
  attn_fwd<<<(SEQ / 64) * 64, 256, 0, stream>>>(QKb, Vtb, attnb);

  // output projection: [8192,1024] x [1024,1024]^T -> out [8192,1024] fp32
  gemm_bt<false><<<(MROWS / 128) * (DMODEL / 128), 256, 0, stream>>>(
      attnb, WOt, out, MROWS, DMODEL, DMODEL, DMODEL, 1.f, 0);
}